// Round 11
// baseline (282.480 us; speedup 1.0000x reference)
//
#include <hip/hip_runtime.h>
#include <hip/hip_bf16.h>
#include <math.h>

#define BB 64
#define NN 256
#define D_VIS 2048
#define D_LBL 512
#define HH 8
#define FF 256
#define DG 2048   // D_GAT = H*F
#define DE 512    // D_EMB
#define ALPHA 0.2f
#define PSTRIDE 264  // Pl row stride in shorts (256 + 8 pad)

using bf16 = __hip_bfloat16;
using short8 = __attribute__((ext_vector_type(8))) short;
using f32x4  = __attribute__((ext_vector_type(4))) float;
__device__ __forceinline__ float b2f(bf16 x) { return __bfloat162float(x); }
__device__ __forceinline__ unsigned short f2bs(float x) {
    bf16 h = __float2bfloat16(x);
    unsigned short u;
    __builtin_memcpy(&u, &h, 2);
    return u;
}

// ---------------- fused Wh GEMM: one dispatch, no atomics, no memset deps.
// grid (32, 16): y<8 -> WhL row-tile y (K=512) -> WhLbT + srcLp/dstLp partials;
//                y>=8 -> WhV row-tile (y-8)&1, K-slice (y-8)>>1 -> WhVz + srcVp/dstVp.
__global__ void __launch_bounds__(256) k_wh(const float* __restrict__ labels,
                                            const float* __restrict__ visual,
                                            const float* __restrict__ Wg,
                                            unsigned short* __restrict__ WhLbT,
                                            float* __restrict__ WhVz,
                                            const float* __restrict__ aSrc,
                                            const float* __restrict__ aDst,
                                            float* __restrict__ srcLp,
                                            float* __restrict__ dstLp,
                                            float* __restrict__ srcVp,
                                            float* __restrict__ dstVp) {
    __shared__ unsigned short As[32][72];
    __shared__ unsigned short Bs[64][72];
    const int t = threadIdx.x;
    const int w = t >> 6;
    const int lane = t & 63;
    const int l15 = lane & 15, quad = lane >> 4;
    const int n0 = blockIdx.x * 64;
    const int p2 = blockIdx.x & 3;     // quarter of head's 256 cols
    const int y = blockIdx.y;
    const bool isL = (y < 8);
    const int q = y - 8;
    const int m0  = isL ? y * 32 : (q & 1) * 32;
    const int z   = isL ? 0 : (q >> 1);
    const int kb0 = z * 512;
    const float* A = isL ? labels : visual;
    const int lda  = isL ? D_LBL : D_VIS;
    const float* Wb = Wg + (isL ? 0 : (size_t)D_LBL * DG);

    f32x4 acc[2];
    acc[0] = (f32x4){0.f, 0.f, 0.f, 0.f};
    acc[1] = (f32x4){0.f, 0.f, 0.f, 0.f};

    for (int kc = 0; kc < 8; ++kc) {
        const int kb = kb0 + kc * 64;
#pragma unroll
        for (int p = 0; p < 2; ++p) {
            const int idx = t + 256 * p;
            const int r = idx >> 4, q4 = idx & 15;
            const float4 v = *(const float4*)(A + (size_t)(m0 + r) * lda + kb + 4 * q4);
            unsigned short s4[4] = {f2bs(v.x), f2bs(v.y), f2bs(v.z), f2bs(v.w)};
            __builtin_memcpy(&As[r][4 * q4], s4, 8);
        }
#pragma unroll
        for (int p = 0; p < 4; ++p) {
            const int kk = (t >> 4) + 16 * p;
            const int c4 = (t & 15) * 4;
            const float4 v = *(const float4*)(Wb + (size_t)(kb + kk) * DG + n0 + c4);
            Bs[c4 + 0][kk] = f2bs(v.x);
            Bs[c4 + 1][kk] = f2bs(v.y);
            Bs[c4 + 2][kk] = f2bs(v.z);
            Bs[c4 + 3][kk] = f2bs(v.w);
        }
        __syncthreads();
#pragma unroll
        for (int ks = 0; ks < 2; ++ks) {
            const short8 bf = *(const short8*)&Bs[w * 16 + l15][ks * 32 + quad * 8];
#pragma unroll
            for (int mi = 0; mi < 2; ++mi) {
                const short8 af = *(const short8*)&As[mi * 16 + l15][ks * 32 + quad * 8];
                acc[mi] = __builtin_amdgcn_mfma_f32_16x16x32_bf16(af, bf, acc[mi], 0, 0, 0);
            }
        }
        __syncthreads();
    }
    const int col = n0 + w * 16 + l15;
    const int h = col >> 8;
    const float as = aSrc[col], ad = aDst[col];
    if (isL) {
#pragma unroll
        for (int mi = 0; mi < 2; ++mi) {
            unsigned short s4[4];
#pragma unroll
            for (int r = 0; r < 4; ++r) s4[r] = f2bs(acc[mi][r]);
            __builtin_memcpy(&WhLbT[(size_t)col * NN + m0 + mi * 16 + quad * 4], s4, 8);
        }
#pragma unroll
        for (int mi = 0; mi < 2; ++mi)
#pragma unroll
            for (int r = 0; r < 4; ++r) {
                float sv = acc[mi][r] * as;
                float dv = acc[mi][r] * ad;
#pragma unroll
                for (int off = 1; off < 16; off <<= 1) {
                    sv += __shfl_xor(sv, off);
                    dv += __shfl_xor(dv, off);
                }
                if (l15 == 0) {
                    const int row = m0 + mi * 16 + quad * 4 + r;
                    srcLp[(p2 * NN + row) * HH + h] = sv;  // unique writer
                    dstLp[(p2 * NN + row) * HH + h] = dv;
                }
            }
    } else {
        float* Wv = WhVz + (size_t)z * BB * DG;
#pragma unroll
        for (int mi = 0; mi < 2; ++mi)
#pragma unroll
            for (int r = 0; r < 4; ++r)
                Wv[(size_t)(m0 + mi * 16 + quad * 4 + r) * DG + col] = acc[mi][r];
        const int pv = p2 * 4 + z;
#pragma unroll
        for (int mi = 0; mi < 2; ++mi)
#pragma unroll
            for (int r = 0; r < 4; ++r) {
                float sv = acc[mi][r] * as;
                float dv = acc[mi][r] * ad;
#pragma unroll
                for (int off = 1; off < 16; off <<= 1) {
                    sv += __shfl_xor(sv, off);
                    dv += __shfl_xor(dv, off);
                }
                if (l15 == 0) {
                    const int row = m0 + mi * 16 + quad * 4 + r;
                    srcVp[(pv * BB + row) * HH + h] = sv;  // unique writer
                    dstVp[(pv * BB + row) * HH + h] = dv;
                }
            }
    }
}

// ---------------- MFMA GAT: factorized softmax + P@W + register epilogue
// grid (b,h,it) = 64*8*4 blocks, 512 thr (8 waves).
__global__ void __launch_bounds__(512, 4) k_gat(const unsigned short* __restrict__ WhLbT,
                                                const float* __restrict__ WhVz,
                                                const float* __restrict__ srcLp,
                                                const float* __restrict__ dstLp,
                                                const float* __restrict__ srcVp,
                                                const float* __restrict__ dstVp,
                                                const float* __restrict__ adj,
                                                const float* __restrict__ pool_q,
                                                bf16* __restrict__ outb,
                                                float* __restrict__ ps_p) {
    const int bid = blockIdx.x;
    const int it = bid & 3;
    const int h  = (bid >> 2) & 7;
    const int b  = bid >> 5;
    const int i0 = it * 64;
    const int t = threadIdx.x;
    const int w = t >> 6;
    const int lane = t & 63;
    const int l15 = lane & 15, quad = lane >> 4;

    __shared__ __align__(16) unsigned short Pl[64][PSTRIDE]; // 33.8 KB
    __shared__ __align__(16) float dls2[2 * NN];
    __shared__ float slsA[64], slsC[64], slsTE[64], inv[64];

    // c = srcV[b,h] + dstV[b,h] summed over 16 partials each
    float c = 0.f;
#pragma unroll
    for (int p = 0; p < 16; ++p)
        c += srcVp[(p * BB + b) * HH + h] + dstVp[(p * BB + b) * HH + h];
    if (t < NN) {
        float dl = 0.f;
#pragma unroll
        for (int p = 0; p < 4; ++p) dl += dstLp[(p * NN + t) * HH + h];
        dls2[2 * t]     = __expf(dl);
        dls2[2 * t + 1] = __expf(ALPHA * dl);
    }
    if (t < 64) {
        float sl = 0.f;
#pragma unroll
        for (int p = 0; p < 4; ++p) sl += srcLp[(p * NN + i0 + t) * HH + h];
        const float u = c + sl;
        slsA[t]  = __expf(u);
        slsC[t]  = __expf(ALPHA * u);
        slsTE[t] = __expf(-u);
    }
    const int n0 = w * 32;
    float wv[2] = {0.f, 0.f};
#pragma unroll
    for (int z = 0; z < 4; ++z)
#pragma unroll
        for (int ni = 0; ni < 2; ++ni)
            wv[ni] += WhVz[(size_t)z * BB * DG + (size_t)b * DG + h * FF + n0 + ni * 16 + l15];
    __syncthreads();

    // ---- phase 1: masked exp via factorization (unnormalized)
    {
        const int g = lane >> 4, s = lane & 15;
#pragma unroll
        for (int rr = 0; rr < 2; ++rr) {
            const int iloc = w * 8 + rr * 4 + g;
            const int i = i0 + iloc;
            const float Ai = slsA[iloc], Ci = slsC[iloc], TEi = slsTE[iloc];
            float pr[16];
            float sum = 0.f;
#pragma unroll
            for (int jj = 0; jj < 8; ++jj) {
                const int j0 = 2 * s + 32 * jj;
                const float2 av = *(const float2*)(adj + (size_t)i * NN + j0);
                const float4 bd = *(const float4*)&dls2[2 * j0];
                const bool g0 = bd.x > TEi;
                const bool g1 = bd.z > TEi;
                float p0 = (g0 ? Ai : Ci) * (g0 ? bd.x : bd.y);
                float p1 = (g1 ? Ai : Ci) * (g1 ? bd.z : bd.w);
                p0 = av.x > 0.f ? p0 : 0.f;
                p1 = av.y > 0.f ? p1 : 0.f;
                pr[2 * jj] = p0; pr[2 * jj + 1] = p1;
                sum += p0 + p1;
            }
#pragma unroll
            for (int off = 1; off < 16; off <<= 1) sum += __shfl_xor(sum, off);
            if (s == 0) inv[iloc] = 1.0f / sum;
#pragma unroll
            for (int jj = 0; jj < 8; ++jj) {
                const unsigned int pk =
                    ((unsigned int)f2bs(pr[2 * jj + 1]) << 16) | f2bs(pr[2 * jj]);
                *(unsigned int*)&Pl[iloc][2 * s + 32 * jj] = pk;
            }
        }
    }
    __syncthreads();

    // ---- phase 2: out[i0:+64, w*32:+32] = P~ @ WhL (mfma 16x16x32 bf16)
    f32x4 acc[4][2];
#pragma unroll
    for (int mi = 0; mi < 4; ++mi)
#pragma unroll
        for (int ni = 0; ni < 2; ++ni) acc[mi][ni] = (f32x4){0.f, 0.f, 0.f, 0.f};

    const unsigned short* wb = WhLbT + (size_t)(h * FF + n0 + l15) * NN + quad * 8;
    short8 bc0 = *(const short8*)(wb);
    short8 bc1 = *(const short8*)(wb + (size_t)16 * NN);
#pragma unroll
    for (int kc = 0; kc < 8; ++kc) {
        short8 bn0, bn1;
        if (kc < 7) {
            bn0 = *(const short8*)(wb + (kc + 1) * 32);
            bn1 = *(const short8*)(wb + (size_t)16 * NN + (kc + 1) * 32);
        }
        short8 a[4];
#pragma unroll
        for (int mi = 0; mi < 4; ++mi)
            a[mi] = *(const short8*)&Pl[mi * 16 + l15][kc * 32 + quad * 8];
#pragma unroll
        for (int mi = 0; mi < 4; ++mi)
            acc[mi][0] = __builtin_amdgcn_mfma_f32_16x16x32_bf16(a[mi], bc0, acc[mi][0], 0, 0, 0);
#pragma unroll
        for (int mi = 0; mi < 4; ++mi)
            acc[mi][1] = __builtin_amdgcn_mfma_f32_16x16x32_bf16(a[mi], bc1, acc[mi][1], 0, 0, 0);
        bc0 = bn0; bc1 = bn1;
    }

    // ---- register epilogue: normalize + WhV, ELU, direct bf16 store + pool dot
    const float pqv0 = pool_q[h * FF + n0 + l15];
    const float pqv1 = pool_q[h * FF + n0 + 16 + l15];
    float* psrow = ps_p + (size_t)(h * 8 + w) * BB * NN + (size_t)b * NN + i0;
#pragma unroll
    for (int mi = 0; mi < 4; ++mi)
#pragma unroll
        for (int r = 0; r < 4; ++r) {
            const int row = mi * 16 + quad * 4 + r;
            const float ivr = inv[row];
            bf16* orow = outb + ((size_t)(b * NN + i0 + row)) * DG + h * FF + n0;
            float x0 = fmaf(acc[mi][0][r], ivr, wv[0]);
            float x1 = fmaf(acc[mi][1][r], ivr, wv[1]);
            x0 = x0 > 0.f ? x0 : (__expf(x0) - 1.0f);
            x1 = x1 > 0.f ? x1 : (__expf(x1) - 1.0f);
            orow[l15]      = __float2bfloat16(x0);
            orow[16 + l15] = __float2bfloat16(x1);
            float dot = fmaf(x0, pqv0, x1 * pqv1);
#pragma unroll
            for (int off = 1; off < 16; off <<= 1) dot += __shfl_xor(dot, off);
            if (l15 == 0) psrow[row] = dot;
        }
}

// ---------------- k_poolfc: ps_p reduce + softmax + pooled(LDS) + fp32 fc + bias
// grid 64 (one per b), 512 thr (8 waves).
__global__ void __launch_bounds__(512) k_poolfc(const bf16* __restrict__ outb,
                                                const float* __restrict__ ps_p,
                                                const float* __restrict__ fcW,
                                                const float* __restrict__ fcb,
                                                float* __restrict__ out) {
    const int b = blockIdx.x;
    const int t = threadIdx.x;
    __shared__ float part[2][NN];
    __shared__ float wsm[NN];
    __shared__ float redm[4];
    __shared__ float reds[4];
    __shared__ __align__(16) float pooledS[DG]; // 8 KB

    // ---- ps reduction over 64 partial slices
    {
        const int n = t & 255, g = t >> 8;
        float v = 0.f;
#pragma unroll 8
        for (int s = g * 32; s < g * 32 + 32; ++s)
            v += ps_p[(size_t)s * BB * NN + (size_t)b * NN + n];
        part[g][n] = v;
    }
    __syncthreads();
    float v = 0.f, e = 0.f;
    if (t < NN) {
        v = part[0][t] + part[1][t];
        float m = v;
#pragma unroll
        for (int off = 32; off; off >>= 1) m = fmaxf(m, __shfl_xor(m, off));
        if ((t & 63) == 0) redm[t >> 6] = m;
    }
    __syncthreads();
    if (t < NN) {
        const float m = fmaxf(fmaxf(redm[0], redm[1]), fmaxf(redm[2], redm[3]));
        e = __expf(v - m);
        float s = e;
#pragma unroll
        for (int off = 32; off; off >>= 1) s += __shfl_xor(s, off);
        if ((t & 63) == 0) reds[t >> 6] = s;
    }
    __syncthreads();
    if (t < NN) {
        const float s = reds[0] + reds[1] + reds[2] + reds[3];
        wsm[t] = e / s;
    }
    __syncthreads();

    // ---- pooled row into LDS: thread owns 4 consecutive d
    {
        const int d0 = 4 * t;
        float a[4] = {0.f, 0.f, 0.f, 0.f};
        const bf16* base = outb + (size_t)b * NN * DG + d0;
#pragma unroll 4
        for (int n = 0; n < NN; ++n) {
            const float wn = wsm[n];
            bf16 bb[4];
            __builtin_memcpy(bb, base + (size_t)n * DG, 8);
#pragma unroll
            for (int k = 0; k < 4; ++k) a[k] = fmaf(wn, b2f(bb[k]), a[k]);
        }
        *(float4*)&pooledS[d0] = (float4){a[0], a[1], a[2], a[3]};
    }
    __syncthreads();

    // ---- fc: out[b, e] = pooledS . fcW[:, e] + fcb[e]  (fp32 vector)
    {
        const int e1 = t; // 512 cols
        float acc = fcb[e1];
#pragma unroll 8
        for (int d = 0; d < DG; ++d)
            acc = fmaf(pooledS[d], fcW[(size_t)d * DE + e1], acc);
        out[(size_t)b * DE + e1] = acc;
    }
}

extern "C" void kernel_launch(void* const* d_in, const int* in_sizes, int n_in,
                              void* d_out, int out_size, void* d_ws, size_t ws_size,
                              hipStream_t stream) {
    (void)in_sizes; (void)n_in; (void)out_size; (void)ws_size;
    const float* visual = (const float*)d_in[0];
    const float* labels = (const float*)d_in[1];
    const float* adj    = (const float*)d_in[2];
    const float* Wg     = (const float*)d_in[3];
    const float* a_src  = (const float*)d_in[4];
    const float* a_dst  = (const float*)d_in[5];
    const float* pool_q = (const float*)d_in[6];
    const float* fcW    = (const float*)d_in[7];
    const float* fcb    = (const float*)d_in[8];
    float* out = (float*)d_out;

    float* ws_f   = (float*)d_ws;
    float* WhVz   = ws_f;                       // 4*64*2048
    float* srcLp  = WhVz + 4 * BB * DG;         // 4*256*8
    float* dstLp  = srcLp + 4 * NN * HH;        // 4*256*8
    float* srcVp  = dstLp + 4 * NN * HH;        // 16*64*8
    float* dstVp  = srcVp + 16 * BB * HH;       // 16*64*8
    float* ps_p   = dstVp + 16 * BB * HH;       // 64*64*256
    bf16*  outb   = (bf16*)(ps_p + 64 * BB * NN);          // 64*256*2048 bf16
    unsigned short* WhLbT = (unsigned short*)(outb + (size_t)BB * NN * DG); // 2048*256

    k_wh<<<dim3(DG / 64, 16), 256, 0, stream>>>(labels, visual, Wg, WhLbT, WhVz,
                                                a_src, a_dst, srcLp, dstLp, srcVp, dstVp);

    k_gat<<<BB * HH * 4, 512, 0, stream>>>(WhLbT, WhVz, srcLp, dstLp, srcVp, dstVp,
                                           adj, pool_q, outb, ps_p);

    k_poolfc<<<BB, 512, 0, stream>>>(outb, ps_p, fcW, fcb, out);
}

// Round 12
// 186.127 us; speedup vs baseline: 1.5177x; 1.5177x over previous
//
#include <hip/hip_runtime.h>
#include <hip/hip_bf16.h>
#include <math.h>

#define BB 64
#define NN 256
#define D_VIS 2048
#define D_LBL 512
#define HH 8
#define FF 256
#define DG 2048   // D_GAT = H*F
#define DE 512    // D_EMB
#define ALPHA 0.2f
#define PSTRIDE 264  // Pl row stride in shorts (256 + 8 pad)

using bf16 = __hip_bfloat16;
using short8 = __attribute__((ext_vector_type(8))) short;
using f32x4  = __attribute__((ext_vector_type(4))) float;
__device__ __forceinline__ float b2f(bf16 x) { return __bfloat162float(x); }
__device__ __forceinline__ unsigned short f2bs(float x) {
    bf16 h = __float2bfloat16(x);
    unsigned short u;
    __builtin_memcpy(&u, &h, 2);
    return u;
}

// ---------------- fused Wh GEMM: one dispatch, no atomics, no memset deps.
// grid (32, 16): y<8 -> WhL row-tile y (K=512) -> WhLbT + srcLp/dstLp partials;
//                y>=8 -> WhV row-tile (y-8)&1, K-slice (y-8)>>1 -> WhVz + srcVp/dstVp.
__global__ void __launch_bounds__(256) k_wh(const float* __restrict__ labels,
                                            const float* __restrict__ visual,
                                            const float* __restrict__ Wg,
                                            unsigned short* __restrict__ WhLbT,
                                            float* __restrict__ WhVz,
                                            const float* __restrict__ aSrc,
                                            const float* __restrict__ aDst,
                                            float* __restrict__ srcLp,
                                            float* __restrict__ dstLp,
                                            float* __restrict__ srcVp,
                                            float* __restrict__ dstVp) {
    __shared__ unsigned short As[32][72];
    __shared__ unsigned short Bs[64][72];
    const int t = threadIdx.x;
    const int w = t >> 6;
    const int lane = t & 63;
    const int l15 = lane & 15, quad = lane >> 4;
    const int n0 = blockIdx.x * 64;
    const int p2 = blockIdx.x & 3;     // quarter of head's 256 cols
    const int y = blockIdx.y;
    const bool isL = (y < 8);
    const int q = y - 8;
    const int m0  = isL ? y * 32 : (q & 1) * 32;
    const int z   = isL ? 0 : (q >> 1);
    const int kb0 = z * 512;
    const float* A = isL ? labels : visual;
    const int lda  = isL ? D_LBL : D_VIS;
    const float* Wb = Wg + (isL ? 0 : (size_t)D_LBL * DG);

    f32x4 acc[2];
    acc[0] = (f32x4){0.f, 0.f, 0.f, 0.f};
    acc[1] = (f32x4){0.f, 0.f, 0.f, 0.f};

    for (int kc = 0; kc < 8; ++kc) {
        const int kb = kb0 + kc * 64;
#pragma unroll
        for (int p = 0; p < 2; ++p) {
            const int idx = t + 256 * p;
            const int r = idx >> 4, q4 = idx & 15;
            const float4 v = *(const float4*)(A + (size_t)(m0 + r) * lda + kb + 4 * q4);
            unsigned short s4[4] = {f2bs(v.x), f2bs(v.y), f2bs(v.z), f2bs(v.w)};
            __builtin_memcpy(&As[r][4 * q4], s4, 8);
        }
#pragma unroll
        for (int p = 0; p < 4; ++p) {
            const int kk = (t >> 4) + 16 * p;
            const int c4 = (t & 15) * 4;
            const float4 v = *(const float4*)(Wb + (size_t)(kb + kk) * DG + n0 + c4);
            Bs[c4 + 0][kk] = f2bs(v.x);
            Bs[c4 + 1][kk] = f2bs(v.y);
            Bs[c4 + 2][kk] = f2bs(v.z);
            Bs[c4 + 3][kk] = f2bs(v.w);
        }
        __syncthreads();
#pragma unroll
        for (int ks = 0; ks < 2; ++ks) {
            const short8 bf = *(const short8*)&Bs[w * 16 + l15][ks * 32 + quad * 8];
#pragma unroll
            for (int mi = 0; mi < 2; ++mi) {
                const short8 af = *(const short8*)&As[mi * 16 + l15][ks * 32 + quad * 8];
                acc[mi] = __builtin_amdgcn_mfma_f32_16x16x32_bf16(af, bf, acc[mi], 0, 0, 0);
            }
        }
        __syncthreads();
    }
    const int col = n0 + w * 16 + l15;
    const int h = col >> 8;
    const float as = aSrc[col], ad = aDst[col];
    if (isL) {
#pragma unroll
        for (int mi = 0; mi < 2; ++mi) {
            unsigned short s4[4];
#pragma unroll
            for (int r = 0; r < 4; ++r) s4[r] = f2bs(acc[mi][r]);
            __builtin_memcpy(&WhLbT[(size_t)col * NN + m0 + mi * 16 + quad * 4], s4, 8);
        }
#pragma unroll
        for (int mi = 0; mi < 2; ++mi)
#pragma unroll
            for (int r = 0; r < 4; ++r) {
                float sv = acc[mi][r] * as;
                float dv = acc[mi][r] * ad;
#pragma unroll
                for (int off = 1; off < 16; off <<= 1) {
                    sv += __shfl_xor(sv, off);
                    dv += __shfl_xor(dv, off);
                }
                if (l15 == 0) {
                    const int row = m0 + mi * 16 + quad * 4 + r;
                    srcLp[(p2 * NN + row) * HH + h] = sv;  // unique writer
                    dstLp[(p2 * NN + row) * HH + h] = dv;
                }
            }
    } else {
        float* Wv = WhVz + (size_t)z * BB * DG;
#pragma unroll
        for (int mi = 0; mi < 2; ++mi)
#pragma unroll
            for (int r = 0; r < 4; ++r)
                Wv[(size_t)(m0 + mi * 16 + quad * 4 + r) * DG + col] = acc[mi][r];
        const int pv = p2 * 4 + z;
#pragma unroll
        for (int mi = 0; mi < 2; ++mi)
#pragma unroll
            for (int r = 0; r < 4; ++r) {
                float sv = acc[mi][r] * as;
                float dv = acc[mi][r] * ad;
#pragma unroll
                for (int off = 1; off < 16; off <<= 1) {
                    sv += __shfl_xor(sv, off);
                    dv += __shfl_xor(dv, off);
                }
                if (l15 == 0) {
                    const int row = m0 + mi * 16 + quad * 4 + r;
                    srcVp[(pv * BB + row) * HH + h] = sv;  // unique writer
                    dstVp[(pv * BB + row) * HH + h] = dv;
                }
            }
    }
}

// ---------------- MFMA GAT: factorized softmax + P@W + register epilogue
// grid (b,h,it) = 64*8*4 blocks, 512 thr (8 waves).
__global__ void __launch_bounds__(512, 4) k_gat(const unsigned short* __restrict__ WhLbT,
                                                const float* __restrict__ WhVz,
                                                const float* __restrict__ srcLp,
                                                const float* __restrict__ dstLp,
                                                const float* __restrict__ srcVp,
                                                const float* __restrict__ dstVp,
                                                const float* __restrict__ adj,
                                                const float* __restrict__ pool_q,
                                                bf16* __restrict__ outb,
                                                float* __restrict__ ps_p) {
    const int bid = blockIdx.x;
    const int it = bid & 3;
    const int h  = (bid >> 2) & 7;
    const int b  = bid >> 5;
    const int i0 = it * 64;
    const int t = threadIdx.x;
    const int w = t >> 6;
    const int lane = t & 63;
    const int l15 = lane & 15, quad = lane >> 4;

    __shared__ __align__(16) unsigned short Pl[64][PSTRIDE]; // 33.8 KB
    __shared__ __align__(16) float dls2[2 * NN];
    __shared__ float slsA[64], slsC[64], slsTE[64], inv[64];

    float c = 0.f;
#pragma unroll
    for (int p = 0; p < 16; ++p)
        c += srcVp[(p * BB + b) * HH + h] + dstVp[(p * BB + b) * HH + h];
    if (t < NN) {
        float dl = 0.f;
#pragma unroll
        for (int p = 0; p < 4; ++p) dl += dstLp[(p * NN + t) * HH + h];
        dls2[2 * t]     = __expf(dl);
        dls2[2 * t + 1] = __expf(ALPHA * dl);
    }
    if (t < 64) {
        float sl = 0.f;
#pragma unroll
        for (int p = 0; p < 4; ++p) sl += srcLp[(p * NN + i0 + t) * HH + h];
        const float u = c + sl;
        slsA[t]  = __expf(u);
        slsC[t]  = __expf(ALPHA * u);
        slsTE[t] = __expf(-u);
    }
    const int n0 = w * 32;
    float wv[2] = {0.f, 0.f};
#pragma unroll
    for (int z = 0; z < 4; ++z)
#pragma unroll
        for (int ni = 0; ni < 2; ++ni)
            wv[ni] += WhVz[(size_t)z * BB * DG + (size_t)b * DG + h * FF + n0 + ni * 16 + l15];
    __syncthreads();

    // ---- phase 1: masked exp via factorization (unnormalized)
    {
        const int g = lane >> 4, s = lane & 15;
#pragma unroll
        for (int rr = 0; rr < 2; ++rr) {
            const int iloc = w * 8 + rr * 4 + g;
            const int i = i0 + iloc;
            const float Ai = slsA[iloc], Ci = slsC[iloc], TEi = slsTE[iloc];
            float pr[16];
            float sum = 0.f;
#pragma unroll
            for (int jj = 0; jj < 8; ++jj) {
                const int j0 = 2 * s + 32 * jj;
                const float2 av = *(const float2*)(adj + (size_t)i * NN + j0);
                const float4 bd = *(const float4*)&dls2[2 * j0];
                const bool g0 = bd.x > TEi;
                const bool g1 = bd.z > TEi;
                float p0 = (g0 ? Ai : Ci) * (g0 ? bd.x : bd.y);
                float p1 = (g1 ? Ai : Ci) * (g1 ? bd.z : bd.w);
                p0 = av.x > 0.f ? p0 : 0.f;
                p1 = av.y > 0.f ? p1 : 0.f;
                pr[2 * jj] = p0; pr[2 * jj + 1] = p1;
                sum += p0 + p1;
            }
#pragma unroll
            for (int off = 1; off < 16; off <<= 1) sum += __shfl_xor(sum, off);
            if (s == 0) inv[iloc] = 1.0f / sum;
#pragma unroll
            for (int jj = 0; jj < 8; ++jj) {
                const unsigned int pk =
                    ((unsigned int)f2bs(pr[2 * jj + 1]) << 16) | f2bs(pr[2 * jj]);
                *(unsigned int*)&Pl[iloc][2 * s + 32 * jj] = pk;
            }
        }
    }
    __syncthreads();

    // ---- phase 2: out[i0:+64, w*32:+32] = P~ @ WhL (mfma 16x16x32 bf16)
    f32x4 acc[4][2];
#pragma unroll
    for (int mi = 0; mi < 4; ++mi)
#pragma unroll
        for (int ni = 0; ni < 2; ++ni) acc[mi][ni] = (f32x4){0.f, 0.f, 0.f, 0.f};

    const unsigned short* wb = WhLbT + (size_t)(h * FF + n0 + l15) * NN + quad * 8;
    short8 bc0 = *(const short8*)(wb);
    short8 bc1 = *(const short8*)(wb + (size_t)16 * NN);
#pragma unroll
    for (int kc = 0; kc < 8; ++kc) {
        short8 bn0, bn1;
        if (kc < 7) {
            bn0 = *(const short8*)(wb + (kc + 1) * 32);
            bn1 = *(const short8*)(wb + (size_t)16 * NN + (kc + 1) * 32);
        }
        short8 a[4];
#pragma unroll
        for (int mi = 0; mi < 4; ++mi)
            a[mi] = *(const short8*)&Pl[mi * 16 + l15][kc * 32 + quad * 8];
#pragma unroll
        for (int mi = 0; mi < 4; ++mi)
            acc[mi][0] = __builtin_amdgcn_mfma_f32_16x16x32_bf16(a[mi], bc0, acc[mi][0], 0, 0, 0);
#pragma unroll
        for (int mi = 0; mi < 4; ++mi)
            acc[mi][1] = __builtin_amdgcn_mfma_f32_16x16x32_bf16(a[mi], bc1, acc[mi][1], 0, 0, 0);
        bc0 = bn0; bc1 = bn1;
    }

    // ---- register epilogue: normalize + WhV, ELU, direct bf16 store + pool dot
    const float pqv0 = pool_q[h * FF + n0 + l15];
    const float pqv1 = pool_q[h * FF + n0 + 16 + l15];
    float* psrow = ps_p + (size_t)(h * 8 + w) * BB * NN + (size_t)b * NN + i0;
#pragma unroll
    for (int mi = 0; mi < 4; ++mi)
#pragma unroll
        for (int r = 0; r < 4; ++r) {
            const int row = mi * 16 + quad * 4 + r;
            const float ivr = inv[row];
            bf16* orow = outb + ((size_t)(b * NN + i0 + row)) * DG + h * FF + n0;
            float x0 = fmaf(acc[mi][0][r], ivr, wv[0]);
            float x1 = fmaf(acc[mi][1][r], ivr, wv[1]);
            x0 = x0 > 0.f ? x0 : (__expf(x0) - 1.0f);
            x1 = x1 > 0.f ? x1 : (__expf(x1) - 1.0f);
            orow[l15]      = __float2bfloat16(x0);
            orow[16 + l15] = __float2bfloat16(x1);
            float dot = fmaf(x0, pqv0, x1 * pqv1);
#pragma unroll
            for (int off = 1; off < 16; off <<= 1) dot += __shfl_xor(dot, off);
            if (l15 == 0) psrow[row] = dot;
        }
}

// ---------------- k_pool: ps_p reduce + softmax + pooled (+ bias-init of out)
// grid (8 dtiles, 64 b), 256 thr; thread owns ONE d col (2B coalesced loads).
__global__ void __launch_bounds__(256) k_pool(const bf16* __restrict__ outb,
                                              const float* __restrict__ ps_p,
                                              float* __restrict__ pooled,
                                              const float* __restrict__ fcb,
                                              float* __restrict__ out) {
    const int dt = blockIdx.x;  // 0..7
    const int b  = blockIdx.y;  // 0..63
    const int t  = threadIdx.x;
    if (dt < 2) out[b * DE + dt * 256 + t] = fcb[dt * 256 + t];
    __shared__ float wsm[NN];
    __shared__ float redm[4];
    __shared__ float reds[4];
    float v = 0.f;
#pragma unroll 8
    for (int s = 0; s < 64; ++s)
        v += ps_p[(size_t)s * BB * NN + (size_t)b * NN + t];
    float m = v;
#pragma unroll
    for (int off = 32; off; off >>= 1) m = fmaxf(m, __shfl_xor(m, off));
    if ((t & 63) == 0) redm[t >> 6] = m;
    __syncthreads();
    m = fmaxf(fmaxf(redm[0], redm[1]), fmaxf(redm[2], redm[3]));
    const float e = __expf(v - m);
    float s = e;
#pragma unroll
    for (int off = 32; off; off >>= 1) s += __shfl_xor(s, off);
    if ((t & 63) == 0) reds[t >> 6] = s;
    __syncthreads();
    s = reds[0] + reds[1] + reds[2] + reds[3];
    wsm[t] = e / s;
    __syncthreads();
    const int d = dt * 256 + t;
    float acc = 0.f;
    const bf16* base = outb + (size_t)b * NN * DG + d;
#pragma unroll 8
    for (int n = 0; n < NN; ++n)
        acc = fmaf(wsm[n], b2f(base[(size_t)n * DG]), acc);
    pooled[(size_t)b * DG + d] = acc;
}

// ---------------- fc GEMM: atomic ksplit into bias-init out
__global__ void __launch_bounds__(256) k_mgemm(const float* __restrict__ A, int lda,
                                               const float* __restrict__ W, int ldw,
                                               float* __restrict__ C, int ldc,
                                               int kSlice, int kIters) {
    __shared__ unsigned short As[32][72];
    __shared__ unsigned short Bs[64][72];
    const int t = threadIdx.x;
    const int w = t >> 6;
    const int lane = t & 63;
    const int l15 = lane & 15, quad = lane >> 4;
    const int n0 = blockIdx.x * 64;
    const int m0 = blockIdx.y * 32;
    const int kb0 = blockIdx.z * kSlice;
    f32x4 acc[2];
    acc[0] = (f32x4){0.f, 0.f, 0.f, 0.f};
    acc[1] = (f32x4){0.f, 0.f, 0.f, 0.f};
    for (int kc = 0; kc < kIters; ++kc) {
        const int kb = kb0 + kc * 64;
#pragma unroll
        for (int p = 0; p < 2; ++p) {
            const int idx = t + 256 * p;
            const int r = idx >> 4, q4 = idx & 15;
            const float4 v = *(const float4*)(A + (size_t)(m0 + r) * lda + kb + 4 * q4);
            unsigned short s4[4] = {f2bs(v.x), f2bs(v.y), f2bs(v.z), f2bs(v.w)};
            __builtin_memcpy(&As[r][4 * q4], s4, 8);
        }
#pragma unroll
        for (int p = 0; p < 4; ++p) {
            const int kk = (t >> 4) + 16 * p;
            const int c4 = (t & 15) * 4;
            const float4 v = *(const float4*)(W + (size_t)(kb + kk) * ldw + n0 + c4);
            Bs[c4 + 0][kk] = f2bs(v.x);
            Bs[c4 + 1][kk] = f2bs(v.y);
            Bs[c4 + 2][kk] = f2bs(v.z);
            Bs[c4 + 3][kk] = f2bs(v.w);
        }
        __syncthreads();
#pragma unroll
        for (int ks = 0; ks < 2; ++ks) {
            const short8 bf = *(const short8*)&Bs[w * 16 + l15][ks * 32 + quad * 8];
#pragma unroll
            for (int mi = 0; mi < 2; ++mi) {
                const short8 af = *(const short8*)&As[mi * 16 + l15][ks * 32 + quad * 8];
                acc[mi] = __builtin_amdgcn_mfma_f32_16x16x32_bf16(af, bf, acc[mi], 0, 0, 0);
            }
        }
        __syncthreads();
    }
    const int col = n0 + w * 16 + l15;
#pragma unroll
    for (int mi = 0; mi < 2; ++mi)
#pragma unroll
        for (int r = 0; r < 4; ++r)
            atomicAdd(&C[(size_t)(m0 + mi * 16 + quad * 4 + r) * ldc + col], acc[mi][r]);
}

extern "C" void kernel_launch(void* const* d_in, const int* in_sizes, int n_in,
                              void* d_out, int out_size, void* d_ws, size_t ws_size,
                              hipStream_t stream) {
    (void)in_sizes; (void)n_in; (void)out_size; (void)ws_size;
    const float* visual = (const float*)d_in[0];
    const float* labels = (const float*)d_in[1];
    const float* adj    = (const float*)d_in[2];
    const float* Wg     = (const float*)d_in[3];
    const float* a_src  = (const float*)d_in[4];
    const float* a_dst  = (const float*)d_in[5];
    const float* pool_q = (const float*)d_in[6];
    const float* fcW    = (const float*)d_in[7];
    const float* fcb    = (const float*)d_in[8];
    float* out = (float*)d_out;

    float* ws_f   = (float*)d_ws;
    float* WhVz   = ws_f;                       // 4*64*2048
    float* srcLp  = WhVz + 4 * BB * DG;         // 4*256*8
    float* dstLp  = srcLp + 4 * NN * HH;        // 4*256*8
    float* srcVp  = dstLp + 4 * NN * HH;        // 16*64*8
    float* dstVp  = srcVp + 16 * BB * HH;       // 16*64*8
    float* ps_p   = dstVp + 16 * BB * HH;       // 64*64*256
    float* pooled = ps_p + 64 * BB * NN;        // 64*2048
    bf16*  outb   = (bf16*)(pooled + BB * DG);  // 64*256*2048 bf16
    unsigned short* WhLbT = (unsigned short*)(outb + (size_t)BB * NN * DG); // 2048*256

    k_wh<<<dim3(DG / 64, 16), 256, 0, stream>>>(labels, visual, Wg, WhLbT, WhVz,
                                                a_src, a_dst, srcLp, dstLp, srcVp, dstVp);

    k_gat<<<BB * HH * 4, 512, 0, stream>>>(WhLbT, WhVz, srcLp, dstLp, srcVp, dstVp,
                                           adj, pool_q, outb, ps_p);

    k_pool<<<dim3(8, BB), 256, 0, stream>>>(outb, ps_p, pooled, fcb, out);

    k_mgemm<<<dim3(DE / 64, BB / 32, 8), 256, 0, stream>>>(
        pooled, DG, fcW, DE, out, DE, 256, 4);
}